// Round 6
// baseline (957.905 us; speedup 1.0000x reference)
//
#include <hip/hip_runtime.h>

typedef unsigned short u16;
using bf16x8 = __attribute__((ext_vector_type(8))) __bf16;
using f32x4  = __attribute__((ext_vector_type(4))) float;
using u16x4  = __attribute__((ext_vector_type(4))) unsigned short;

#define D_DIM 1024
#define F_DIM 4096

// ---------------- Cayley table (Cl(3,0)), compile-time ----------------
struct Cayley { int k[8][8]; int s[8][8]; };
constexpr Cayley make_cayley() {
    Cayley c{};
    const int gens[8][3] = {{0,0,0},{1,0,0},{2,0,0},{3,0,0},{1,2,0},{1,3,0},{2,3,0},{1,2,3}};
    const int glen[8] = {0,1,1,1,2,2,2,3};
    const int mask2idx[8] = {0,1,2,4,3,5,6,7};
    for (int i = 0; i < 8; ++i) {
        for (int j = 0; j < 8; ++j) {
            int g[6] = {0,0,0,0,0,0};
            int n = 0;
            for (int t = 0; t < glen[i]; ++t) g[n++] = gens[i][t];
            for (int t = 0; t < glen[j]; ++t) g[n++] = gens[j][t];
            int sign = 1;
            bool changed = true;
            while (changed) {
                changed = false;
                int t = 0;
                while (t + 1 < n) {
                    if (g[t] == g[t+1]) {
                        for (int u = t; u + 2 < n; ++u) g[u] = g[u+2];
                        n -= 2; changed = true;
                        if (t > 0) --t;
                    } else if (g[t] > g[t+1]) {
                        int tmp = g[t]; g[t] = g[t+1]; g[t+1] = tmp;
                        sign = -sign; changed = true; ++t;
                    } else {
                        ++t;
                    }
                }
            }
            int mask = 0;
            for (int t = 0; t < n; ++t) mask |= 1 << (g[t] - 1);
            c.k[i][j] = mask2idx[mask];
            c.s[i][j] = sign;
        }
    }
    return c;
}
constexpr Cayley CAY = make_cayley();

// ---------------- helpers ----------------
__device__ __forceinline__ u16 f2bf(float f) {           // RNE f32->bf16
    unsigned u = __float_as_uint(f);
    unsigned r = 0x7FFFu + ((u >> 16) & 1u);
    return (u16)((u + r) >> 16);
}

__device__ __forceinline__ void gload16(const u16* g, const u16* l) {
    __builtin_amdgcn_global_load_lds(
        (const __attribute__((address_space(1))) void*)g,
        (__attribute__((address_space(3))) void*)l, 16, 0, 0);
}

// swizzled LDS fragment read: tile is [256][64] u16, row-linear with slot^=(row&7)
__device__ __forceinline__ bf16x8 frag(const u16* tile, int row, int ks, int lane) {
    const int slot = ((ks << 2) + (lane >> 4)) ^ (lane & 7);
    return *(const bf16x8*)(tile + row * 64 + slot * 8);
}

// ---------------- weight transpose f32 [R][C] -> bf16 [C][R], with optional
// gate/up chunk interleave: mode 0 plain, 1 gate (chunks even), 2 up (odd) ----
__global__ __launch_bounds__(256) void transpose_kernel(
    const float* __restrict__ in, u16* __restrict__ outp, int R, int C, int mode)
{
    __shared__ float tile[32][33];
    const int tx = threadIdx.x & 31, ty = threadIdx.x >> 5;
    const int c0 = blockIdx.x * 32, r0 = blockIdx.y * 32;
    #pragma unroll
    for (int t = 0; t < 4; ++t)
        tile[ty + t*8][tx] = in[(size_t)(r0 + ty + t*8) * C + c0 + tx];
    __syncthreads();
    #pragma unroll
    for (int t = 0; t < 4; ++t) {
        const int c = c0 + ty + t*8;
        int orow;
        if (mode == 0)      orow = c;
        else if (mode == 1) orow = ((c >> 4) << 5) + (c & 15);
        else                orow = ((c >> 4) << 5) + 16 + (c & 15);
        outp[(size_t)orow * R + r0 + tx] = f2bf(tile[tx][ty + t*8]);
    }
}

// ---------------- fused geometric product + mix + LayerNorm -> bf16 flat ----------------
__global__ __launch_bounds__(256, 2) void geo_ln_kernel(
    const float* __restrict__ x, const float* __restrict__ iw,
    const float* __restrict__ gg, const float* __restrict__ lnw,
    const float* __restrict__ lnb, u16* __restrict__ flat)
{
    __shared__ float wsig[64];
    __shared__ float red[4][16];
    const int tid = threadIdx.x;
    if (tid < 64) wsig[tid] = 1.f / (1.f + __expf(-iw[tid]));
    __syncthreads();
    const float g   = 1.f / (1.f + __expf(-gg[0]));
    const float gm1 = 1.f - g;

    float coef[64];
    #pragma unroll
    for (int t = 0; t < 64; ++t) coef[t] = (float)CAY.s[t >> 3][t & 7] * wsig[t];

    const int n  = blockIdx.x;
    const int d0 = tid * 4;
    const float* xb = x + (size_t)n * 8 * D_DIM;
    f32x4 xv[8];
    #pragma unroll
    for (int i = 0; i < 8; ++i) xv[i] = __builtin_nontemporal_load((const f32x4*)(xb + i * D_DIM + d0));

    float mix[8][4];
    #pragma unroll
    for (int s4 = 0; s4 < 4; ++s4) {
        float xs[8];
        #pragma unroll
        for (int i = 0; i < 8; ++i) xs[i] = xv[i][s4];
        float geo[8] = {0.f,0.f,0.f,0.f,0.f,0.f,0.f,0.f};
        #pragma unroll
        for (int i = 0; i < 8; ++i) {
            #pragma unroll
            for (int j = 0; j < 8; ++j) {
                geo[CAY.k[i][j]] = fmaf(coef[i*8+j] * xs[i], xs[j], geo[CAY.k[i][j]]);
            }
        }
        #pragma unroll
        for (int k = 0; k < 8; ++k) mix[k][s4] = g * geo[k] + gm1 * xs[k];
    }

    float s1[8], s2[8];
    #pragma unroll
    for (int k = 0; k < 8; ++k) {
        s1[k] = 0.f; s2[k] = 0.f;
        #pragma unroll
        for (int s4 = 0; s4 < 4; ++s4) {
            s1[k] += mix[k][s4];
            s2[k]  = fmaf(mix[k][s4], mix[k][s4], s2[k]);
        }
    }
    #pragma unroll
    for (int m = 1; m < 64; m <<= 1) {
        #pragma unroll
        for (int k = 0; k < 8; ++k) {
            s1[k] += __shfl_xor(s1[k], m, 64);
            s2[k] += __shfl_xor(s2[k], m, 64);
        }
    }
    const int wave = tid >> 6, lane = tid & 63;
    if (lane == 0) {
        #pragma unroll
        for (int k = 0; k < 8; ++k) { red[wave][k] = s1[k]; red[wave][8+k] = s2[k]; }
    }
    __syncthreads();
    float mean[8], rstd[8];
    #pragma unroll
    for (int k = 0; k < 8; ++k) {
        float a = red[0][k] + red[1][k] + red[2][k] + red[3][k];
        float b = red[0][8+k] + red[1][8+k] + red[2][8+k] + red[3][8+k];
        float mu  = a * (1.f / 1024.f);
        float var = b * (1.f / 1024.f) - mu * mu;
        mean[k] = mu;
        rstd[k] = rsqrtf(var + 1e-5f);
    }
    f32x4 lw = *(const f32x4*)(lnw + d0);
    f32x4 lb = *(const f32x4*)(lnb + d0);
    #pragma unroll
    for (int k = 0; k < 8; ++k) {
        u16x4 o;
        #pragma unroll
        for (int s4 = 0; s4 < 4; ++s4) {
            float v = (mix[k][s4] - mean[k]) * rstd[k] * lw[s4] + lb[s4];
            o[s4] = f2bf(v);
        }
        *(u16x4*)(flat + ((size_t)(n * 8 + k)) * D_DIM + d0) = o;
    }
}

// ================= persistent multi-tile 256x256 8-wave pipelined GEMM =================
// A [M][KDIM] bf16, B [N][KDIM] bf16 (B^T). EPI=1: swiglu-pack -> h bf16 (nt).
// EPI=0: out = X + acc, f32 (nt).
// One generation: grid 256, each block chains TILES output tiles through ONE
// software pipeline (K-step sequence s = 0..TILES*NT-1). Staging for s+1/s+2
// crosses tile boundaries (coords computed per step). Per-tile epilogue runs
// between ph4-barrier and next ph1; its 64 VMEM ops enter the vmcnt queue, so
// the first post-boundary ph1 uses vmcnt(63) (completes the 4 needed oldest
// loads; over-counts epilogue ops). ph4-end vmcnt(8) drains all epilogue ops
// and restores the exact steady-state queue. Steady ledger (audited):
//   ph1-end vmcnt(6): completes A1(s),B1(s)   [issued ph1/ph2 of s-1]
//   ph4-end vmcnt(8): completes A0(s+1),B0(s+1) [issued ph3/ph4 of s-1]
template<int KDIM, bool S1, bool S2, int W1T, int W4>
__device__ __forceinline__ void ktile(
    int s, const u16* __restrict__ A, const u16* __restrict__ B,
    u16 (*As)[256][64], u16 (*Bs)[256][64],
    int brow1, int bcol1, int k1, int brow2, int bcol2, int k2, bool bigw1,
    int wave, int lane, int wm, int wn, int fr,
    f32x4 (&acc)[8][4])
{
    const int buf = s & 1;
    const int nbuf = (s + 1) & 1;
    const u16* At = &As[buf][0][0];
    const u16* Bt = &Bs[buf][0][0];
    const int sr = lane >> 3, sslot = (lane & 7) ^ sr;

    bf16x8 af[4][2], bf[4][2];

    // ---- phase 1: quadrant (0,0) ----
    #pragma unroll
    for (int m = 0; m < 4; ++m)
        #pragma unroll
        for (int ks = 0; ks < 2; ++ks)
            af[m][ks] = frag(At, wm*64 + m*16 + fr, ks, lane);
    #pragma unroll
    for (int n = 0; n < 2; ++n)
        #pragma unroll
        for (int ks = 0; ks < 2; ++ks)
            bf[n][ks] = frag(Bt, wn*32 + n*16 + fr, ks, lane);
    if (S1) {
        #pragma unroll
        for (int q = 0; q < 2; ++q) {
            const int idx_w = q*512 + wave*64;
            const int row = (idx_w >> 3) + sr;
            gload16(A + (size_t)(brow1 + 128 + row)*KDIM + k1*64 + sslot*8,
                    &As[nbuf][128][0] + idx_w*8);
        }
    }
    __builtin_amdgcn_s_setprio(1);
    #pragma unroll
    for (int m = 0; m < 4; ++m)
        #pragma unroll
        for (int n = 0; n < 2; ++n)
            #pragma unroll
            for (int ks = 0; ks < 2; ++ks)
                acc[m][n] = __builtin_amdgcn_mfma_f32_16x16x32_bf16(af[m][ks], bf[n][ks], acc[m][n], 0, 0, 0);
    __builtin_amdgcn_s_setprio(0);
    if constexpr (W1T == 6) {
        if (bigw1) asm volatile("s_waitcnt vmcnt(63)" ::: "memory");
        else       asm volatile("s_waitcnt vmcnt(6)" ::: "memory");
    } else {
        asm volatile("s_waitcnt vmcnt(0)" ::: "memory");
    }
    __builtin_amdgcn_s_barrier();
    __builtin_amdgcn_sched_barrier(0);

    // ---- phase 2: quadrant (0,1) ----
    #pragma unroll
    for (int n = 0; n < 2; ++n)
        #pragma unroll
        for (int ks = 0; ks < 2; ++ks)
            bf[2+n][ks] = frag(Bt, 128 + wn*32 + n*16 + fr, ks, lane);
    if (S1) {
        #pragma unroll
        for (int q = 0; q < 2; ++q) {
            const int idx_w = q*512 + wave*64;
            const int row = (idx_w >> 3) + sr;
            gload16(B + (size_t)(bcol1 + 128 + row)*KDIM + k1*64 + sslot*8,
                    &Bs[nbuf][128][0] + idx_w*8);
        }
    }
    __builtin_amdgcn_s_setprio(1);
    #pragma unroll
    for (int m = 0; m < 4; ++m)
        #pragma unroll
        for (int n = 0; n < 2; ++n)
            #pragma unroll
            for (int ks = 0; ks < 2; ++ks)
                acc[m][2+n] = __builtin_amdgcn_mfma_f32_16x16x32_bf16(af[m][ks], bf[2+n][ks], acc[m][2+n], 0, 0, 0);
    __builtin_amdgcn_s_setprio(0);
    __builtin_amdgcn_s_barrier();
    __builtin_amdgcn_sched_barrier(0);

    // ---- phase 3: quadrant (1,0) ----
    #pragma unroll
    for (int m = 0; m < 4; ++m)
        #pragma unroll
        for (int ks = 0; ks < 2; ++ks)
            af[m][ks] = frag(At, 128 + wm*64 + m*16 + fr, ks, lane);
    if (S2) {
        #pragma unroll
        for (int q = 0; q < 2; ++q) {
            const int idx_w = q*512 + wave*64;
            const int row = (idx_w >> 3) + sr;
            gload16(A + (size_t)(brow2 + row)*KDIM + k2*64 + sslot*8,
                    &As[buf][0][0] + idx_w*8);
        }
    }
    __builtin_amdgcn_s_setprio(1);
    #pragma unroll
    for (int m = 0; m < 4; ++m)
        #pragma unroll
        for (int n = 0; n < 2; ++n)
            #pragma unroll
            for (int ks = 0; ks < 2; ++ks)
                acc[4+m][n] = __builtin_amdgcn_mfma_f32_16x16x32_bf16(af[m][ks], bf[n][ks], acc[4+m][n], 0, 0, 0);
    __builtin_amdgcn_s_setprio(0);
    __builtin_amdgcn_s_barrier();
    __builtin_amdgcn_sched_barrier(0);

    // ---- phase 4: quadrant (1,1) ----
    if (S2) {
        #pragma unroll
        for (int q = 0; q < 2; ++q) {
            const int idx_w = q*512 + wave*64;
            const int row = (idx_w >> 3) + sr;
            gload16(B + (size_t)(bcol2 + row)*KDIM + k2*64 + sslot*8,
                    &Bs[buf][0][0] + idx_w*8);
        }
    }
    __builtin_amdgcn_s_setprio(1);
    #pragma unroll
    for (int m = 0; m < 4; ++m)
        #pragma unroll
        for (int n = 0; n < 2; ++n)
            #pragma unroll
            for (int ks = 0; ks < 2; ++ks)
                acc[4+m][2+n] = __builtin_amdgcn_mfma_f32_16x16x32_bf16(af[m][ks], bf[2+n][ks], acc[4+m][2+n], 0, 0, 0);
    __builtin_amdgcn_s_setprio(0);
    if constexpr (W4 == 8)      asm volatile("s_waitcnt vmcnt(8)" ::: "memory");
    else if constexpr (W4 == 4) asm volatile("s_waitcnt vmcnt(4)" ::: "memory");
    __builtin_amdgcn_s_barrier();
    __builtin_amdgcn_sched_barrier(0);
}

template<int EPI>
__device__ __forceinline__ void tile_epilogue(
    f32x4 (&acc)[8][4], void* __restrict__ OUT, const float* __restrict__ X,
    int Ncols, int browE, int bcolE, int wm, int wn, int fr, int fq)
{
    if constexpr (EPI == 1) {
        u16* H = (u16*)OUT;
        const int Nh = Ncols >> 1;
        #pragma unroll
        for (int qm = 0; qm < 2; ++qm)
            #pragma unroll
            for (int m = 0; m < 4; ++m) {
                const int row = browE + qm*128 + wm*64 + m*16 + fq*4;
                #pragma unroll
                for (int qn = 0; qn < 2; ++qn) {
                    const int col = (bcolE >> 1) + qn*64 + wn*16 + fr;
                    f32x4 g = acc[qm*4+m][qn*2+0];
                    f32x4 u = acc[qm*4+m][qn*2+1];
                    #pragma unroll
                    for (int r = 0; r < 4; ++r) {
                        float gv = g[r], uv = u[r];
                        float hv = (gv / (1.f + __expf(-gv))) * uv;
                        __builtin_nontemporal_store(f2bf(hv), &H[(size_t)(row + r) * Nh + col]);
                    }
                }
            }
    } else {
        float* Of = (float*)OUT;
        #pragma unroll
        for (int mi = 0; mi < 8; ++mi) {
            const int row = browE + (mi>>2)*128 + wm*64 + (mi&3)*16 + fq*4;
            #pragma unroll
            for (int ni = 0; ni < 4; ++ni) {
                const int col = bcolE + (ni>>1)*128 + wn*32 + (ni&1)*16 + fr;
                #pragma unroll
                for (int r = 0; r < 4; ++r) {
                    float xv = __builtin_nontemporal_load(&X[(size_t)(row+r)*Ncols + col]);
                    __builtin_nontemporal_store(xv + acc[mi][ni][r], &Of[(size_t)(row+r)*Ncols + col]);
                }
            }
        }
    }
    #pragma unroll
    for (int i = 0; i < 8; ++i)
        #pragma unroll
        for (int j = 0; j < 4; ++j) acc[i][j] = {0.f, 0.f, 0.f, 0.f};
}

template<int KDIM, int EPI, int TILES>
__global__ __launch_bounds__(512, 2) void gemm8ph(
    const u16* __restrict__ A, const u16* __restrict__ B,
    const float* __restrict__ X, void* __restrict__ OUT, int Ncols)
{
    constexpr int NT  = KDIM / 64;
    constexpr int LNT = __builtin_ctz(NT);
    constexpr int TS  = TILES * NT;
    __shared__ alignas(16) u16 As[2][256][64];
    __shared__ alignas(16) u16 Bs[2][256][64];

    const int bid = blockIdx.x;
    int brow0, bcol0, drow, dcol;
    if constexpr (EPI == 1) {
        // GEMM1: 256 blocks = 8 XCD x (4 cols x 8 rowgroups). Fixed col per
        // block (B strip 2 MiB L2-resident per XCD); 16 row-panels chained.
        const int xcd = bid & 7, idx = bid >> 3;
        brow0 = (idx >> 2) * (TILES << 8);
        bcol0 = (xcd * 4 + (idx & 3)) << 8;
        drow = 256; dcol = 0;
    } else {
        // GEMM2: 256 blocks = 128 rows x 2 colpairs; block owns 2 col-tiles of
        // one row-panel (h panel read 2x total instead of 4x; A L2-hot).
        brow0 = (bid >> 1) << 8;
        bcol0 = (bid & 1) * (TILES << 8);
        drow = 0; dcol = 256;
    }

    const int tid = threadIdx.x;
    const int wave = tid >> 6, lane = tid & 63;
    const int wm = wave >> 2, wn = wave & 3;
    const int fr = lane & 15, fq = lane >> 4;
    const int sr = lane >> 3, sslot = (lane & 7) ^ sr;

    f32x4 acc[8][4];
    #pragma unroll
    for (int i = 0; i < 8; ++i)
        #pragma unroll
        for (int j = 0; j < 4; ++j) acc[i][j] = {0.f, 0.f, 0.f, 0.f};

    // ---- prologue: stage A0(0),B0(0),A1(0),B1(0),A0(1),B0(1) (all tile 0) ----
    #pragma unroll
    for (int q = 0; q < 2; ++q) {
        const int idx_w = q*512 + wave*64;
        const int row = (idx_w >> 3) + sr;
        gload16(A + (size_t)(brow0 + row)*KDIM + sslot*8,          &As[0][0][0]   + idx_w*8);
    }
    #pragma unroll
    for (int q = 0; q < 2; ++q) {
        const int idx_w = q*512 + wave*64;
        const int row = (idx_w >> 3) + sr;
        gload16(B + (size_t)(bcol0 + row)*KDIM + sslot*8,          &Bs[0][0][0]   + idx_w*8);
    }
    #pragma unroll
    for (int q = 0; q < 2; ++q) {
        const int idx_w = q*512 + wave*64;
        const int row = (idx_w >> 3) + sr;
        gload16(A + (size_t)(brow0 + 128 + row)*KDIM + sslot*8,    &As[0][128][0] + idx_w*8);
    }
    #pragma unroll
    for (int q = 0; q < 2; ++q) {
        const int idx_w = q*512 + wave*64;
        const int row = (idx_w >> 3) + sr;
        gload16(B + (size_t)(bcol0 + 128 + row)*KDIM + sslot*8,    &Bs[0][128][0] + idx_w*8);
    }
    #pragma unroll
    for (int q = 0; q < 2; ++q) {
        const int idx_w = q*512 + wave*64;
        const int row = (idx_w >> 3) + sr;
        gload16(A + (size_t)(brow0 + row)*KDIM + 64 + sslot*8,     &As[1][0][0]   + idx_w*8);
    }
    #pragma unroll
    for (int q = 0; q < 2; ++q) {
        const int idx_w = q*512 + wave*64;
        const int row = (idx_w >> 3) + sr;
        gload16(B + (size_t)(bcol0 + row)*KDIM + 64 + sslot*8,     &Bs[1][0][0]   + idx_w*8);
    }
    asm volatile("s_waitcnt vmcnt(8)" ::: "memory");
    __builtin_amdgcn_s_barrier();
    __builtin_amdgcn_sched_barrier(0);

    // ---- main chained loop over TS = TILES*NT K-steps ----
    int s = 0;
    #pragma unroll 1
    for (; s < TS - 2; ++s) {
        const int s1 = s + 1, s2 = s + 2;
        const int tl1 = s1 >> LNT, k1 = s1 & (NT - 1);
        const int tl2 = s2 >> LNT, k2 = s2 & (NT - 1);
        const bool bigw1 = (s > 0) && ((s & (NT - 1)) == 0);
        ktile<KDIM, true, true, 6, 8>(s, A, B, As, Bs,
            brow0 + tl1*drow, bcol0 + tl1*dcol, k1,
            brow0 + tl2*drow, bcol0 + tl2*dcol, k2, bigw1,
            wave, lane, wm, wn, fr, acc);
        if ((s1 & (NT - 1)) == 0) {
            const int tl = s >> LNT;
            tile_epilogue<EPI>(acc, OUT, X, Ncols, brow0 + tl*drow, bcol0 + tl*dcol, wm, wn, fr, fq);
        }
    }
    // s = TS-2: stage A1/B1 of last step only
    {
        const int s1 = s + 1;
        const int tl1 = s1 >> LNT, k1 = s1 & (NT - 1);
        ktile<KDIM, true, false, 6, 4>(s, A, B, As, Bs,
            brow0 + tl1*drow, bcol0 + tl1*dcol, k1, 0, 0, 0, false,
            wave, lane, wm, wn, fr, acc);
        ++s;
    }
    // s = TS-1: full drain at ph1
    ktile<KDIM, false, false, 0, -1>(s, A, B, As, Bs, 0, 0, 0, 0, 0, 0, false,
        wave, lane, wm, wn, fr, acc);
    tile_epilogue<EPI>(acc, OUT, X, Ncols,
        brow0 + (TILES-1)*drow, bcol0 + (TILES-1)*dcol, wm, wn, fr, fq);
}

// ---------------- launch ----------------
extern "C" void kernel_launch(void* const* d_in, const int* in_sizes, int n_in,
                              void* d_out, int out_size, void* d_ws, size_t ws_size,
                              hipStream_t stream) {
    const float* x     = (const float*)d_in[0];
    const float* iw    = (const float*)d_in[1];
    const float* gg    = (const float*)d_in[2];
    const float* lnw   = (const float*)d_in[3];
    const float* lnb   = (const float*)d_in[4];
    const float* wgate = (const float*)d_in[5];
    const float* wup   = (const float*)d_in[6];
    const float* wdown = (const float*)d_in[7];
    float* out = (float*)d_out;

    const int ntok = in_sizes[0] / (8 * D_DIM);   // 4096
    const int M    = ntok * 8;                    // 32768

    const size_t flat_b = (size_t)M * D_DIM * 2;          //  64 MiB
    const size_t wc_b   = (size_t)2 * D_DIM * F_DIM * 2;  //  16 MiB (combined gate+up)
    const size_t wd_b   = (size_t)D_DIM * F_DIM * 2;      //   8 MiB
    const size_t h_b    = (size_t)M * F_DIM * 2;          // 256 MiB
    const size_t need   = flat_b + wc_b + wd_b + h_b;
    if (ws_size < need) return;

    char* ws = (char*)d_ws;
    u16* flat = (u16*)(ws);
    u16* wc   = (u16*)(ws + flat_b);
    u16* wdt  = (u16*)(ws + flat_b + wc_b);
    u16* h    = (u16*)(ws + flat_b + wc_b + wd_b);

    transpose_kernel<<<dim3(F_DIM/32, D_DIM/32), 256, 0, stream>>>(wgate, wc,  D_DIM, F_DIM, 1);
    transpose_kernel<<<dim3(F_DIM/32, D_DIM/32), 256, 0, stream>>>(wup,   wc,  D_DIM, F_DIM, 2);
    transpose_kernel<<<dim3(D_DIM/32, F_DIM/32), 256, 0, stream>>>(wdown, wdt, F_DIM, D_DIM, 0);
    geo_ln_kernel<<<dim3(ntok), 256, 0, stream>>>(x, iw, gg, lnw, lnb, flat);

    // GEMM1: [32768][1024] x [8192][1024]^T -> swiglu-pack -> h [32768][4096]
    gemm8ph<D_DIM, 1, 16><<<dim3(256), 512, 0, stream>>>(flat, wc, nullptr, h, 2*F_DIM);
    // GEMM2: [32768][4096] x [1024][4096]^T + x -> out [32768][1024]
    gemm8ph<F_DIM, 0, 2><<<dim3(256), 512, 0, stream>>>(h, wdt, x, out, D_DIM);
}

// Round 7
// 941.632 us; speedup vs baseline: 1.0173x; 1.0173x over previous
//
#include <hip/hip_runtime.h>

typedef unsigned short u16;
using bf16x8 = __attribute__((ext_vector_type(8))) __bf16;
using f32x4  = __attribute__((ext_vector_type(4))) float;
using f32x16 = __attribute__((ext_vector_type(16))) float;
using u16x4  = __attribute__((ext_vector_type(4))) unsigned short;

#define D_DIM 1024
#define F_DIM 4096

// ---------------- Cayley table (Cl(3,0)), compile-time ----------------
struct Cayley { int k[8][8]; int s[8][8]; };
constexpr Cayley make_cayley() {
    Cayley c{};
    const int gens[8][3] = {{0,0,0},{1,0,0},{2,0,0},{3,0,0},{1,2,0},{1,3,0},{2,3,0},{1,2,3}};
    const int glen[8] = {0,1,1,1,2,2,2,3};
    const int mask2idx[8] = {0,1,2,4,3,5,6,7};
    for (int i = 0; i < 8; ++i) {
        for (int j = 0; j < 8; ++j) {
            int g[6] = {0,0,0,0,0,0};
            int n = 0;
            for (int t = 0; t < glen[i]; ++t) g[n++] = gens[i][t];
            for (int t = 0; t < glen[j]; ++t) g[n++] = gens[j][t];
            int sign = 1;
            bool changed = true;
            while (changed) {
                changed = false;
                int t = 0;
                while (t + 1 < n) {
                    if (g[t] == g[t+1]) {
                        for (int u = t; u + 2 < n; ++u) g[u] = g[u+2];
                        n -= 2; changed = true;
                        if (t > 0) --t;
                    } else if (g[t] > g[t+1]) {
                        int tmp = g[t]; g[t] = g[t+1]; g[t+1] = tmp;
                        sign = -sign; changed = true; ++t;
                    } else {
                        ++t;
                    }
                }
            }
            int mask = 0;
            for (int t = 0; t < n; ++t) mask |= 1 << (g[t] - 1);
            c.k[i][j] = mask2idx[mask];
            c.s[i][j] = sign;
        }
    }
    return c;
}
constexpr Cayley CAY = make_cayley();

// ---------------- helpers ----------------
__device__ __forceinline__ u16 f2bf(float f) {           // RNE f32->bf16
    unsigned u = __float_as_uint(f);
    unsigned r = 0x7FFFu + ((u >> 16) & 1u);
    return (u16)((u + r) >> 16);
}

__device__ __forceinline__ void gload16(const u16* g, const u16* l) {
    __builtin_amdgcn_global_load_lds(
        (const __attribute__((address_space(1))) void*)g,
        (__attribute__((address_space(3))) void*)l, 16, 0, 0);
}

// swizzled LDS fragment read for 32x32x16 MFMA: tile [256][64] u16,
// LDS[r][j] = global[r][j ^ (r&7)]. Lane wants row rowbase+(lane&31),
// u16 block j = kk*2 + (lane>>5)  (k = kk*16 + 8*(lane>>5) + e).
__device__ __forceinline__ bf16x8 frag32(const u16* tile, int rowbase, int kk, int lane) {
    const int r = rowbase + (lane & 31);
    const int slot = ((kk << 1) + (lane >> 5)) ^ (r & 7);
    return *(const bf16x8*)(tile + r * 64 + slot * 8);
}

// ---------------- weight transpose f32 [R][C] -> bf16 [C][R], with optional
// gate/up 128-col block interleave: mode 0 plain, 1 gate, 2 up ----
__global__ __launch_bounds__(256) void transpose_kernel(
    const float* __restrict__ in, u16* __restrict__ outp, int R, int C, int mode)
{
    __shared__ float tile[32][33];
    const int tx = threadIdx.x & 31, ty = threadIdx.x >> 5;
    const int c0 = blockIdx.x * 32, r0 = blockIdx.y * 32;
    #pragma unroll
    for (int t = 0; t < 4; ++t)
        tile[ty + t*8][tx] = in[(size_t)(r0 + ty + t*8) * C + c0 + tx];
    __syncthreads();
    #pragma unroll
    for (int t = 0; t < 4; ++t) {
        const int c = c0 + ty + t*8;
        int orow;
        if (mode == 0)      orow = c;
        else if (mode == 1) orow = ((c >> 7) << 8) + (c & 127);
        else                orow = ((c >> 7) << 8) + 128 + (c & 127);
        outp[(size_t)orow * R + r0 + tx] = f2bf(tile[tx][ty + t*8]);
    }
}

// ---------------- fused geometric product + mix + LayerNorm -> bf16 flat ----------------
__global__ __launch_bounds__(256, 2) void geo_ln_kernel(
    const float* __restrict__ x, const float* __restrict__ iw,
    const float* __restrict__ gg, const float* __restrict__ lnw,
    const float* __restrict__ lnb, u16* __restrict__ flat)
{
    __shared__ float wsig[64];
    __shared__ float red[4][16];
    const int tid = threadIdx.x;
    if (tid < 64) wsig[tid] = 1.f / (1.f + __expf(-iw[tid]));
    __syncthreads();
    const float g   = 1.f / (1.f + __expf(-gg[0]));
    const float gm1 = 1.f - g;

    float coef[64];
    #pragma unroll
    for (int t = 0; t < 64; ++t) coef[t] = (float)CAY.s[t >> 3][t & 7] * wsig[t];

    const int n  = blockIdx.x;
    const int d0 = tid * 4;
    const float* xb = x + (size_t)n * 8 * D_DIM;
    f32x4 xv[8];
    #pragma unroll
    for (int i = 0; i < 8; ++i) xv[i] = __builtin_nontemporal_load((const f32x4*)(xb + i * D_DIM + d0));

    float mix[8][4];
    #pragma unroll
    for (int s4 = 0; s4 < 4; ++s4) {
        float xs[8];
        #pragma unroll
        for (int i = 0; i < 8; ++i) xs[i] = xv[i][s4];
        float geo[8] = {0.f,0.f,0.f,0.f,0.f,0.f,0.f,0.f};
        #pragma unroll
        for (int i = 0; i < 8; ++i) {
            #pragma unroll
            for (int j = 0; j < 8; ++j) {
                geo[CAY.k[i][j]] = fmaf(coef[i*8+j] * xs[i], xs[j], geo[CAY.k[i][j]]);
            }
        }
        #pragma unroll
        for (int k = 0; k < 8; ++k) mix[k][s4] = g * geo[k] + gm1 * xs[k];
    }

    float s1[8], s2[8];
    #pragma unroll
    for (int k = 0; k < 8; ++k) {
        s1[k] = 0.f; s2[k] = 0.f;
        #pragma unroll
        for (int s4 = 0; s4 < 4; ++s4) {
            s1[k] += mix[k][s4];
            s2[k]  = fmaf(mix[k][s4], mix[k][s4], s2[k]);
        }
    }
    #pragma unroll
    for (int m = 1; m < 64; m <<= 1) {
        #pragma unroll
        for (int k = 0; k < 8; ++k) {
            s1[k] += __shfl_xor(s1[k], m, 64);
            s2[k] += __shfl_xor(s2[k], m, 64);
        }
    }
    const int wave = tid >> 6, lane = tid & 63;
    if (lane == 0) {
        #pragma unroll
        for (int k = 0; k < 8; ++k) { red[wave][k] = s1[k]; red[wave][8+k] = s2[k]; }
    }
    __syncthreads();
    float mean[8], rstd[8];
    #pragma unroll
    for (int k = 0; k < 8; ++k) {
        float a = red[0][k] + red[1][k] + red[2][k] + red[3][k];
        float b = red[0][8+k] + red[1][8+k] + red[2][8+k] + red[3][8+k];
        float mu  = a * (1.f / 1024.f);
        float var = b * (1.f / 1024.f) - mu * mu;
        mean[k] = mu;
        rstd[k] = rsqrtf(var + 1e-5f);
    }
    f32x4 lw = *(const f32x4*)(lnw + d0);
    f32x4 lb = *(const f32x4*)(lnb + d0);
    #pragma unroll
    for (int k = 0; k < 8; ++k) {
        u16x4 o;
        #pragma unroll
        for (int s4 = 0; s4 < 4; ++s4) {
            float v = (mix[k][s4] - mean[k]) * rstd[k] * lw[s4] + lb[s4];
            o[s4] = f2bf(v);
        }
        *(u16x4*)(flat + ((size_t)(n * 8 + k)) * D_DIM + d0) = o;
    }
}

// ================= 256x256 8-wave pipelined GEMM, 32x32x16 MFMA =================
// A [M][KDIM] bf16, B [N][KDIM] bf16 (B^T layout).
// EPI=1: B is gate/up packed in 128-row blocks (rows p*256..+127 = gate cols
//        p*128..+127, +128..+255 = up). Wave's qn=0 tile = gate, qn=1 = up,
//        matching lanes/regs -> in-register silu fusion. h bf16 (nt stores).
// EPI=0: out = X + acc, f32 (nt).
// Schedule (round-4/5, ledger verified): 4 phases/K-step; reads ph1 A-half0(8)
// +B-qn0(4), ph2 B-qn1(4), ph3 A-half1(8), ph4 0; stages ph1->A1(t+1),
// ph2->B1(t+1), ph3->A0(t+2), ph4->B0(t+2); waits ph1-end vmcnt(6),
// ph4-end vmcnt(8); tail drains 6/4 then 0.
template<int KDIM, bool S1, bool S2, int W1, int W4>
__device__ __forceinline__ void ktile(
    int t, const u16* __restrict__ A, const u16* __restrict__ B,
    u16 (*As)[256][64], u16 (*Bs)[256][64],
    int brow, int bcol, int wave, int lane, int wm, int wn,
    f32x16 (&acc)[4][2])
{
    const int buf = t & 1;
    const u16* At = &As[buf][0][0];
    const u16* Bt = &Bs[buf][0][0];
    const int sr = lane >> 3, sslot = (lane & 7) ^ sr;

    bf16x8 af[2][4], bf0[4], bf1[4];

    // ---- phase 1: (qm0, qn0) ----
    #pragma unroll
    for (int mt = 0; mt < 2; ++mt)
        #pragma unroll
        for (int kk = 0; kk < 4; ++kk)
            af[mt][kk] = frag32(At, wm*64 + mt*32, kk, lane);
    #pragma unroll
    for (int kk = 0; kk < 4; ++kk)
        bf0[kk] = frag32(Bt, wn*32, kk, lane);
    if (S1) {
        #pragma unroll
        for (int q = 0; q < 2; ++q) {
            const int idx_w = q*512 + wave*64;
            const int row = (idx_w >> 3) + sr;
            gload16(A + (size_t)(brow + 128 + row)*KDIM + (t+1)*64 + sslot*8,
                    &As[(t+1)&1][128][0] + idx_w*8);
        }
    }
    __builtin_amdgcn_s_setprio(1);
    #pragma unroll
    for (int mt = 0; mt < 2; ++mt)
        #pragma unroll
        for (int kk = 0; kk < 4; ++kk)
            acc[mt][0] = __builtin_amdgcn_mfma_f32_32x32x16_bf16(af[mt][kk], bf0[kk], acc[mt][0], 0, 0, 0);
    __builtin_amdgcn_s_setprio(0);
    if constexpr (W1 == 6) asm volatile("s_waitcnt vmcnt(6)" ::: "memory");
    else                   asm volatile("s_waitcnt vmcnt(0)" ::: "memory");
    __builtin_amdgcn_s_barrier();
    __builtin_amdgcn_sched_barrier(0);

    // ---- phase 2: (qm0, qn1) ----
    #pragma unroll
    for (int kk = 0; kk < 4; ++kk)
        bf1[kk] = frag32(Bt, 128 + wn*32, kk, lane);
    if (S1) {
        #pragma unroll
        for (int q = 0; q < 2; ++q) {
            const int idx_w = q*512 + wave*64;
            const int row = (idx_w >> 3) + sr;
            gload16(B + (size_t)(bcol + 128 + row)*KDIM + (t+1)*64 + sslot*8,
                    &Bs[(t+1)&1][128][0] + idx_w*8);
        }
    }
    __builtin_amdgcn_s_setprio(1);
    #pragma unroll
    for (int mt = 0; mt < 2; ++mt)
        #pragma unroll
        for (int kk = 0; kk < 4; ++kk)
            acc[mt][1] = __builtin_amdgcn_mfma_f32_32x32x16_bf16(af[mt][kk], bf1[kk], acc[mt][1], 0, 0, 0);
    __builtin_amdgcn_s_setprio(0);
    __builtin_amdgcn_s_barrier();
    __builtin_amdgcn_sched_barrier(0);

    // ---- phase 3: (qm1, qn0) ----
    #pragma unroll
    for (int mt = 0; mt < 2; ++mt)
        #pragma unroll
        for (int kk = 0; kk < 4; ++kk)
            af[mt][kk] = frag32(At, 128 + wm*64 + mt*32, kk, lane);
    if (S2) {
        #pragma unroll
        for (int q = 0; q < 2; ++q) {
            const int idx_w = q*512 + wave*64;
            const int row = (idx_w >> 3) + sr;
            gload16(A + (size_t)(brow + row)*KDIM + (t+2)*64 + sslot*8,
                    &As[buf][0][0] + idx_w*8);
        }
    }
    __builtin_amdgcn_s_setprio(1);
    #pragma unroll
    for (int mt = 0; mt < 2; ++mt)
        #pragma unroll
        for (int kk = 0; kk < 4; ++kk)
            acc[2+mt][0] = __builtin_amdgcn_mfma_f32_32x32x16_bf16(af[mt][kk], bf0[kk], acc[2+mt][0], 0, 0, 0);
    __builtin_amdgcn_s_setprio(0);
    __builtin_amdgcn_s_barrier();
    __builtin_amdgcn_sched_barrier(0);

    // ---- phase 4: (qm1, qn1) ----
    if (S2) {
        #pragma unroll
        for (int q = 0; q < 2; ++q) {
            const int idx_w = q*512 + wave*64;
            const int row = (idx_w >> 3) + sr;
            gload16(B + (size_t)(bcol + row)*KDIM + (t+2)*64 + sslot*8,
                    &Bs[buf][0][0] + idx_w*8);
        }
    }
    __builtin_amdgcn_s_setprio(1);
    #pragma unroll
    for (int mt = 0; mt < 2; ++mt)
        #pragma unroll
        for (int kk = 0; kk < 4; ++kk)
            acc[2+mt][1] = __builtin_amdgcn_mfma_f32_32x32x16_bf16(af[mt][kk], bf1[kk], acc[2+mt][1], 0, 0, 0);
    __builtin_amdgcn_s_setprio(0);
    if constexpr (W4 == 8)      asm volatile("s_waitcnt vmcnt(8)" ::: "memory");
    else if constexpr (W4 == 4) asm volatile("s_waitcnt vmcnt(4)" ::: "memory");
    __builtin_amdgcn_s_barrier();
    __builtin_amdgcn_sched_barrier(0);
}

template<int KDIM, int EPI>
__global__ __launch_bounds__(512, 2) void gemm8ph(
    const u16* __restrict__ A, const u16* __restrict__ B,
    const float* __restrict__ X, void* __restrict__ OUT, int Ncols)
{
    constexpr int NT = KDIM / 64;
    __shared__ alignas(16) u16 As[2][256][64];
    __shared__ alignas(16) u16 Bs[2][256][64];

    const int nbx = Ncols >> 8;
    const int nwg = gridDim.x;
    const int bid = blockIdx.x;
    int brow, bcol;
    if constexpr (EPI == 1) {
        // XCD column-strip: each XCD owns 4 cols (B strip 2 MiB L2-resident).
        const int xcd = bid & 7, idx = bid >> 3;
        const int cpx = nbx >> 3;
        bcol = (xcd * cpx + (idx & (cpx - 1))) << 8;
        brow = (idx / cpx) << 8;
    } else {
        // standard XCD swizzle (round-4 best for GEMM2)
        const int wg = (bid & 7) * (nwg >> 3) + (bid >> 3);
        brow = (wg / nbx) << 8;
        bcol = (wg % nbx) << 8;
    }

    const int tid = threadIdx.x;
    const int wave = tid >> 6, lane = tid & 63;
    const int wm = wave >> 2, wn = wave & 3;
    const int sr = lane >> 3, sslot = (lane & 7) ^ sr;

    f32x16 acc[4][2];
    #pragma unroll
    for (int i = 0; i < 4; ++i)
        #pragma unroll
        for (int j = 0; j < 2; ++j)
            #pragma unroll
            for (int e = 0; e < 16; ++e) acc[i][j][e] = 0.f;

    // ---- prologue: stage A0(0),B0(0),A1(0),B1(0),A0(1),B0(1) ----
    #pragma unroll
    for (int q = 0; q < 2; ++q) {
        const int idx_w = q*512 + wave*64;
        const int row = (idx_w >> 3) + sr;
        gload16(A + (size_t)(brow + row)*KDIM + sslot*8,          &As[0][0][0]   + idx_w*8);
    }
    #pragma unroll
    for (int q = 0; q < 2; ++q) {
        const int idx_w = q*512 + wave*64;
        const int row = (idx_w >> 3) + sr;
        gload16(B + (size_t)(bcol + row)*KDIM + sslot*8,          &Bs[0][0][0]   + idx_w*8);
    }
    #pragma unroll
    for (int q = 0; q < 2; ++q) {
        const int idx_w = q*512 + wave*64;
        const int row = (idx_w >> 3) + sr;
        gload16(A + (size_t)(brow + 128 + row)*KDIM + sslot*8,    &As[0][128][0] + idx_w*8);
    }
    #pragma unroll
    for (int q = 0; q < 2; ++q) {
        const int idx_w = q*512 + wave*64;
        const int row = (idx_w >> 3) + sr;
        gload16(B + (size_t)(bcol + 128 + row)*KDIM + sslot*8,    &Bs[0][128][0] + idx_w*8);
    }
    #pragma unroll
    for (int q = 0; q < 2; ++q) {
        const int idx_w = q*512 + wave*64;
        const int row = (idx_w >> 3) + sr;
        gload16(A + (size_t)(brow + row)*KDIM + 64 + sslot*8,     &As[1][0][0]   + idx_w*8);
    }
    #pragma unroll
    for (int q = 0; q < 2; ++q) {
        const int idx_w = q*512 + wave*64;
        const int row = (idx_w >> 3) + sr;
        gload16(B + (size_t)(bcol + row)*KDIM + 64 + sslot*8,     &Bs[1][0][0]   + idx_w*8);
    }
    asm volatile("s_waitcnt vmcnt(8)" ::: "memory");
    __builtin_amdgcn_s_barrier();
    __builtin_amdgcn_sched_barrier(0);

    // ---- main loop ----
    #pragma unroll 1
    for (int t = 0; t < NT - 2; ++t)
        ktile<KDIM, true, true, 6, 8>(t, A, B, As, Bs, brow, bcol, wave, lane, wm, wn, acc);
    ktile<KDIM, true,  false, 6, 4>(NT-2, A, B, As, Bs, brow, bcol, wave, lane, wm, wn, acc);
    ktile<KDIM, false, false, 0, -1>(NT-1, A, B, As, Bs, brow, bcol, wave, lane, wm, wn, acc);

    // ---- epilogue (nt stream-out). C/D layout: col=lane&31,
    // row=(reg&3)+8*(reg>>2)+4*(lane>>5) ----
    const int cl = lane & 31, hi4 = (lane >> 5) * 4;
    if constexpr (EPI == 1) {
        u16* H = (u16*)OUT;
        const int Nh = Ncols >> 1;
        const int col = (bcol >> 1) + wn*32 + cl;
        #pragma unroll
        for (int qm = 0; qm < 2; ++qm)
            #pragma unroll
            for (int mt = 0; mt < 2; ++mt) {
                const int rowb = brow + qm*128 + wm*64 + mt*32 + hi4;
                f32x16 g = acc[qm*2+mt][0];
                f32x16 u = acc[qm*2+mt][1];
                #pragma unroll
                for (int reg = 0; reg < 16; ++reg) {
                    const int row = rowb + (reg & 3) + 8*(reg >> 2);
                    float gv = g[reg], uv = u[reg];
                    float hv = (gv / (1.f + __expf(-gv))) * uv;
                    __builtin_nontemporal_store(f2bf(hv), &H[(size_t)row * Nh + col]);
                }
            }
    } else {
        float* Of = (float*)OUT;
        #pragma unroll
        for (int qm = 0; qm < 2; ++qm)
            #pragma unroll
            for (int mt = 0; mt < 2; ++mt) {
                const int rowb = brow + qm*128 + wm*64 + mt*32 + hi4;
                #pragma unroll
                for (int qn = 0; qn < 2; ++qn) {
                    const int col = bcol + qn*128 + wn*32 + cl;
                    #pragma unroll
                    for (int reg = 0; reg < 16; ++reg) {
                        const int row = rowb + (reg & 3) + 8*(reg >> 2);
                        float xv = __builtin_nontemporal_load(&X[(size_t)row*Ncols + col]);
                        __builtin_nontemporal_store(xv + acc[qm*2+mt][qn][reg], &Of[(size_t)row*Ncols + col]);
                    }
                }
            }
    }
}

// ---------------- launch ----------------
extern "C" void kernel_launch(void* const* d_in, const int* in_sizes, int n_in,
                              void* d_out, int out_size, void* d_ws, size_t ws_size,
                              hipStream_t stream) {
    const float* x     = (const float*)d_in[0];
    const float* iw    = (const float*)d_in[1];
    const float* gg    = (const float*)d_in[2];
    const float* lnw   = (const float*)d_in[3];
    const float* lnb   = (const float*)d_in[4];
    const float* wgate = (const float*)d_in[5];
    const float* wup   = (const float*)d_in[6];
    const float* wdown = (const float*)d_in[7];
    float* out = (float*)d_out;

    const int ntok = in_sizes[0] / (8 * D_DIM);   // 4096
    const int M    = ntok * 8;                    // 32768

    const size_t flat_b = (size_t)M * D_DIM * 2;          //  64 MiB
    const size_t wc_b   = (size_t)2 * D_DIM * F_DIM * 2;  //  16 MiB (combined gate+up)
    const size_t wd_b   = (size_t)D_DIM * F_DIM * 2;      //   8 MiB
    const size_t h_b    = (size_t)M * F_DIM * 2;          // 256 MiB
    const size_t need   = flat_b + wc_b + wd_b + h_b;
    if (ws_size < need) return;

    char* ws = (char*)d_ws;
    u16* flat = (u16*)(ws);
    u16* wc   = (u16*)(ws + flat_b);
    u16* wdt  = (u16*)(ws + flat_b + wc_b);
    u16* h    = (u16*)(ws + flat_b + wc_b + wd_b);

    transpose_kernel<<<dim3(F_DIM/32, D_DIM/32), 256, 0, stream>>>(wgate, wc,  D_DIM, F_DIM, 1);
    transpose_kernel<<<dim3(F_DIM/32, D_DIM/32), 256, 0, stream>>>(wup,   wc,  D_DIM, F_DIM, 2);
    transpose_kernel<<<dim3(D_DIM/32, F_DIM/32), 256, 0, stream>>>(wdown, wdt, F_DIM, D_DIM, 0);
    geo_ln_kernel<<<dim3(ntok), 256, 0, stream>>>(x, iw, gg, lnw, lnb, flat);

    // GEMM1: [32768][1024] x [8192][1024]^T -> swiglu (128-col pack) -> h [32768][4096]
    gemm8ph<D_DIM, 1><<<dim3((M/256) * (2*F_DIM/256)), 512, 0, stream>>>(flat, wc, nullptr, h, 2*F_DIM);
    // GEMM2: [32768][4096] x [1024][4096]^T + x -> out [32768][1024]
    gemm8ph<F_DIM, 0><<<dim3((M/256) * (D_DIM/256)), 512, 0, stream>>>(h, wdt, x, out, D_DIM);
}

// Round 8
// 832.178 us; speedup vs baseline: 1.1511x; 1.1315x over previous
//
#include <hip/hip_runtime.h>

typedef unsigned short u16;
using bf16x8 = __attribute__((ext_vector_type(8))) __bf16;
using f32x4  = __attribute__((ext_vector_type(4))) float;
using u16x4  = __attribute__((ext_vector_type(4))) unsigned short;

#define D_DIM 1024
#define F_DIM 4096

// ---------------- Cayley table (Cl(3,0)), compile-time ----------------
struct Cayley { int k[8][8]; int s[8][8]; };
constexpr Cayley make_cayley() {
    Cayley c{};
    const int gens[8][3] = {{0,0,0},{1,0,0},{2,0,0},{3,0,0},{1,2,0},{1,3,0},{2,3,0},{1,2,3}};
    const int glen[8] = {0,1,1,1,2,2,2,3};
    const int mask2idx[8] = {0,1,2,4,3,5,6,7};
    for (int i = 0; i < 8; ++i) {
        for (int j = 0; j < 8; ++j) {
            int g[6] = {0,0,0,0,0,0};
            int n = 0;
            for (int t = 0; t < glen[i]; ++t) g[n++] = gens[i][t];
            for (int t = 0; t < glen[j]; ++t) g[n++] = gens[j][t];
            int sign = 1;
            bool changed = true;
            while (changed) {
                changed = false;
                int t = 0;
                while (t + 1 < n) {
                    if (g[t] == g[t+1]) {
                        for (int u = t; u + 2 < n; ++u) g[u] = g[u+2];
                        n -= 2; changed = true;
                        if (t > 0) --t;
                    } else if (g[t] > g[t+1]) {
                        int tmp = g[t]; g[t] = g[t+1]; g[t+1] = tmp;
                        sign = -sign; changed = true; ++t;
                    } else {
                        ++t;
                    }
                }
            }
            int mask = 0;
            for (int t = 0; t < n; ++t) mask |= 1 << (g[t] - 1);
            c.k[i][j] = mask2idx[mask];
            c.s[i][j] = sign;
        }
    }
    return c;
}
constexpr Cayley CAY = make_cayley();

// ---------------- helpers ----------------
__device__ __forceinline__ u16 f2bf(float f) {           // RNE f32->bf16
    unsigned u = __float_as_uint(f);
    unsigned r = 0x7FFFu + ((u >> 16) & 1u);
    return (u16)((u + r) >> 16);
}

__device__ __forceinline__ void gload16(const u16* g, const u16* l) {
    __builtin_amdgcn_global_load_lds(
        (const __attribute__((address_space(1))) void*)g,
        (__attribute__((address_space(3))) void*)l, 16, 0, 0);
}

// swizzled LDS fragment read: tile is [256][64] u16, row-linear with slot^=(row&7)
__device__ __forceinline__ bf16x8 frag(const u16* tile, int row, int ks, int lane) {
    const int slot = ((ks << 2) + (lane >> 4)) ^ (lane & 7);
    return *(const bf16x8*)(tile + row * 64 + slot * 8);
}

// ---------------- weight transpose f32 [R][C] -> bf16 [C][R], with optional
// gate/up chunk interleave: mode 0 plain, 1 gate (16-col chunks even), 2 up (odd) ----
__global__ __launch_bounds__(256) void transpose_kernel(
    const float* __restrict__ in, u16* __restrict__ outp, int R, int C, int mode)
{
    __shared__ float tile[32][33];
    const int tx = threadIdx.x & 31, ty = threadIdx.x >> 5;
    const int c0 = blockIdx.x * 32, r0 = blockIdx.y * 32;
    #pragma unroll
    for (int t = 0; t < 4; ++t)
        tile[ty + t*8][tx] = in[(size_t)(r0 + ty + t*8) * C + c0 + tx];
    __syncthreads();
    #pragma unroll
    for (int t = 0; t < 4; ++t) {
        const int c = c0 + ty + t*8;
        int orow;
        if (mode == 0)      orow = c;
        else if (mode == 1) orow = ((c >> 4) << 5) + (c & 15);
        else                orow = ((c >> 4) << 5) + 16 + (c & 15);
        outp[(size_t)orow * R + r0 + tx] = f2bf(tile[tx][ty + t*8]);
    }
}

// ---------------- fused geometric product + mix + LayerNorm -> bf16 flat ----------------
__global__ __launch_bounds__(256, 2) void geo_ln_kernel(
    const float* __restrict__ x, const float* __restrict__ iw,
    const float* __restrict__ gg, const float* __restrict__ lnw,
    const float* __restrict__ lnb, u16* __restrict__ flat)
{
    __shared__ float wsig[64];
    __shared__ float red[4][16];
    const int tid = threadIdx.x;
    if (tid < 64) wsig[tid] = 1.f / (1.f + __expf(-iw[tid]));
    __syncthreads();
    const float g   = 1.f / (1.f + __expf(-gg[0]));
    const float gm1 = 1.f - g;

    float coef[64];
    #pragma unroll
    for (int t = 0; t < 64; ++t) coef[t] = (float)CAY.s[t >> 3][t & 7] * wsig[t];

    const int n  = blockIdx.x;
    const int d0 = tid * 4;
    const float* xb = x + (size_t)n * 8 * D_DIM;
    f32x4 xv[8];
    #pragma unroll
    for (int i = 0; i < 8; ++i) xv[i] = __builtin_nontemporal_load((const f32x4*)(xb + i * D_DIM + d0));

    float mix[8][4];
    #pragma unroll
    for (int s4 = 0; s4 < 4; ++s4) {
        float xs[8];
        #pragma unroll
        for (int i = 0; i < 8; ++i) xs[i] = xv[i][s4];
        float geo[8] = {0.f,0.f,0.f,0.f,0.f,0.f,0.f,0.f};
        #pragma unroll
        for (int i = 0; i < 8; ++i) {
            #pragma unroll
            for (int j = 0; j < 8; ++j) {
                geo[CAY.k[i][j]] = fmaf(coef[i*8+j] * xs[i], xs[j], geo[CAY.k[i][j]]);
            }
        }
        #pragma unroll
        for (int k = 0; k < 8; ++k) mix[k][s4] = g * geo[k] + gm1 * xs[k];
    }

    float s1[8], s2[8];
    #pragma unroll
    for (int k = 0; k < 8; ++k) {
        s1[k] = 0.f; s2[k] = 0.f;
        #pragma unroll
        for (int s4 = 0; s4 < 4; ++s4) {
            s1[k] += mix[k][s4];
            s2[k]  = fmaf(mix[k][s4], mix[k][s4], s2[k]);
        }
    }
    #pragma unroll
    for (int m = 1; m < 64; m <<= 1) {
        #pragma unroll
        for (int k = 0; k < 8; ++k) {
            s1[k] += __shfl_xor(s1[k], m, 64);
            s2[k] += __shfl_xor(s2[k], m, 64);
        }
    }
    const int wave = tid >> 6, lane = tid & 63;
    if (lane == 0) {
        #pragma unroll
        for (int k = 0; k < 8; ++k) { red[wave][k] = s1[k]; red[wave][8+k] = s2[k]; }
    }
    __syncthreads();
    float mean[8], rstd[8];
    #pragma unroll
    for (int k = 0; k < 8; ++k) {
        float a = red[0][k] + red[1][k] + red[2][k] + red[3][k];
        float b = red[0][8+k] + red[1][8+k] + red[2][8+k] + red[3][8+k];
        float mu  = a * (1.f / 1024.f);
        float var = b * (1.f / 1024.f) - mu * mu;
        mean[k] = mu;
        rstd[k] = rsqrtf(var + 1e-5f);
    }
    f32x4 lw = *(const f32x4*)(lnw + d0);
    f32x4 lb = *(const f32x4*)(lnb + d0);
    #pragma unroll
    for (int k = 0; k < 8; ++k) {
        u16x4 o;
        #pragma unroll
        for (int s4 = 0; s4 < 4; ++s4) {
            float v = (mix[k][s4] - mean[k]) * rstd[k] * lw[s4] + lb[s4];
            o[s4] = f2bf(v);
        }
        *(u16x4*)(flat + ((size_t)(n * 8 + k)) * D_DIM + d0) = o;
    }
}

// ================= 256x256 8-wave pipelined GEMM, 2 phases/K-step =================
// A [M][KDIM] bf16, B [N][KDIM] bf16 (B^T). EPI=1: swiglu-pack -> h bf16 (nt).
// EPI=0: out = X + acc, f32 (nt).
// 2-phase schedule (halves barrier count vs 4-phase; ledger audited):
//  phA: reads A-half0(8)+bf0(4)+bf1(4); stage A1(t+1),B1(t+1) -> nbuf[128..]
//       (nbuf unread during step t); 32 MFMA (quadrants (0,0),(0,1)); barrier.
//  phB: reads A-half1(8) (bf0/bf1 stay in registers -> Bs[buf] dead after phA);
//       stage A0(t+2),B0(t+2) -> buf[0..127] (half0 dead after phA barrier);
//       32 MFMA ((1,0),(1,1)); vmcnt(4); barrier.
// vmcnt(4)@phB-end completes A0/B0(t+1) and A1/B1(t+1) (8 newer entries kept=4).
// Prologue stages A0(0),B0(0),A1(0),B1(0),A0(1),B0(1) then vmcnt(4).
// Tail: t=NT-2 phB-end vmcnt(0); t=NT-1 no stages/waits.
template<int KDIM, bool S1, bool S2, int W>
__device__ __forceinline__ void ktile2(
    int t, const u16* __restrict__ A, const u16* __restrict__ B,
    u16 (*As)[256][64], u16 (*Bs)[256][64],
    int brow, int bcol, int wave, int lane, int wm, int wn, int fr,
    f32x4 (&acc)[8][4])
{
    const int buf = t & 1;
    const int nbuf = (t + 1) & 1;
    const u16* At = &As[buf][0][0];
    const u16* Bt = &Bs[buf][0][0];
    const int sr = lane >> 3, sslot = (lane & 7) ^ sr;

    bf16x8 af[4][2], bf0[2][2], bf1[2][2];

    // ======== phase A: quadrants (0,0),(0,1) ========
    #pragma unroll
    for (int m = 0; m < 4; ++m)
        #pragma unroll
        for (int ks = 0; ks < 2; ++ks)
            af[m][ks] = frag(At, wm*64 + m*16 + fr, ks, lane);
    #pragma unroll
    for (int n = 0; n < 2; ++n)
        #pragma unroll
        for (int ks = 0; ks < 2; ++ks) {
            bf0[n][ks] = frag(Bt, wn*32 + n*16 + fr, ks, lane);
            bf1[n][ks] = frag(Bt, 128 + wn*32 + n*16 + fr, ks, lane);
        }
    if (S1) {
        #pragma unroll
        for (int q = 0; q < 2; ++q) {
            const int idx_w = q*512 + wave*64;
            const int row = (idx_w >> 3) + sr;
            gload16(A + (size_t)(brow + 128 + row)*KDIM + (t+1)*64 + sslot*8,
                    &As[nbuf][128][0] + idx_w*8);
        }
        #pragma unroll
        for (int q = 0; q < 2; ++q) {
            const int idx_w = q*512 + wave*64;
            const int row = (idx_w >> 3) + sr;
            gload16(B + (size_t)(bcol + 128 + row)*KDIM + (t+1)*64 + sslot*8,
                    &Bs[nbuf][128][0] + idx_w*8);
        }
    }
    __builtin_amdgcn_s_setprio(1);
    #pragma unroll
    for (int m = 0; m < 4; ++m)
        #pragma unroll
        for (int n = 0; n < 2; ++n)
            #pragma unroll
            for (int ks = 0; ks < 2; ++ks) {
                acc[m][n]   = __builtin_amdgcn_mfma_f32_16x16x32_bf16(af[m][ks], bf0[n][ks], acc[m][n],   0, 0, 0);
                acc[m][2+n] = __builtin_amdgcn_mfma_f32_16x16x32_bf16(af[m][ks], bf1[n][ks], acc[m][2+n], 0, 0, 0);
            }
    __builtin_amdgcn_s_setprio(0);
    __builtin_amdgcn_s_barrier();
    __builtin_amdgcn_sched_barrier(0);

    // ======== phase B: quadrants (1,0),(1,1) ========
    #pragma unroll
    for (int m = 0; m < 4; ++m)
        #pragma unroll
        for (int ks = 0; ks < 2; ++ks)
            af[m][ks] = frag(At, 128 + wm*64 + m*16 + fr, ks, lane);
    if (S2) {
        #pragma unroll
        for (int q = 0; q < 2; ++q) {
            const int idx_w = q*512 + wave*64;
            const int row = (idx_w >> 3) + sr;
            gload16(A + (size_t)(brow + row)*KDIM + (t+2)*64 + sslot*8,
                    &As[buf][0][0] + idx_w*8);
        }
        #pragma unroll
        for (int q = 0; q < 2; ++q) {
            const int idx_w = q*512 + wave*64;
            const int row = (idx_w >> 3) + sr;
            gload16(B + (size_t)(bcol + row)*KDIM + (t+2)*64 + sslot*8,
                    &Bs[buf][0][0] + idx_w*8);
        }
    }
    __builtin_amdgcn_s_setprio(1);
    #pragma unroll
    for (int m = 0; m < 4; ++m)
        #pragma unroll
        for (int n = 0; n < 2; ++n)
            #pragma unroll
            for (int ks = 0; ks < 2; ++ks) {
                acc[4+m][n]   = __builtin_amdgcn_mfma_f32_16x16x32_bf16(af[m][ks], bf0[n][ks], acc[4+m][n],   0, 0, 0);
                acc[4+m][2+n] = __builtin_amdgcn_mfma_f32_16x16x32_bf16(af[m][ks], bf1[n][ks], acc[4+m][2+n], 0, 0, 0);
            }
    __builtin_amdgcn_s_setprio(0);
    if constexpr (W == 4)      asm volatile("s_waitcnt vmcnt(4)" ::: "memory");
    else if constexpr (W == 0) asm volatile("s_waitcnt vmcnt(0)" ::: "memory");
    __builtin_amdgcn_s_barrier();
    __builtin_amdgcn_sched_barrier(0);
}

template<int KDIM, int EPI>
__global__ __launch_bounds__(512, 2) void gemm8ph(
    const u16* __restrict__ A, const u16* __restrict__ B,
    const float* __restrict__ X, void* __restrict__ OUT, int Ncols)
{
    constexpr int NT = KDIM / 64;
    __shared__ alignas(16) u16 As[2][256][64];
    __shared__ alignas(16) u16 Bs[2][256][64];

    const int nbx = Ncols >> 8;
    const int nwg = gridDim.x;
    const int bid = blockIdx.x;
    int brow, bcol;
    if constexpr (EPI == 1) {
        // XCD column-strip (round-5 best for GEMM1): each XCD owns nbx/8 cols;
        // its B strip (4 cols x 256 x 1024 x 2B = 2 MiB) stays L2-resident.
        const int xcd = bid & 7, idx = bid >> 3;
        const int cpx = nbx >> 3;
        bcol = (xcd * cpx + (idx & (cpx - 1))) << 8;
        brow = (idx / cpx) << 8;
    } else {
        // standard XCD swizzle (round-4 best for GEMM2)
        const int wg = (bid & 7) * (nwg >> 3) + (bid >> 3);
        brow = (wg / nbx) << 8;
        bcol = (wg % nbx) << 8;
    }

    const int tid = threadIdx.x;
    const int wave = tid >> 6, lane = tid & 63;
    const int wm = wave >> 2, wn = wave & 3;
    const int fr = lane & 15, fq = lane >> 4;
    const int sr = lane >> 3, sslot = (lane & 7) ^ sr;

    f32x4 acc[8][4];
    #pragma unroll
    for (int i = 0; i < 8; ++i)
        #pragma unroll
        for (int j = 0; j < 4; ++j) acc[i][j] = {0.f, 0.f, 0.f, 0.f};

    // ---- prologue: stage A0(0),B0(0),A1(0),B1(0),A0(1),B0(1) ----
    #pragma unroll
    for (int q = 0; q < 2; ++q) {
        const int idx_w = q*512 + wave*64;
        const int row = (idx_w >> 3) + sr;
        gload16(A + (size_t)(brow + row)*KDIM + sslot*8,          &As[0][0][0]   + idx_w*8);
    }
    #pragma unroll
    for (int q = 0; q < 2; ++q) {
        const int idx_w = q*512 + wave*64;
        const int row = (idx_w >> 3) + sr;
        gload16(B + (size_t)(bcol + row)*KDIM + sslot*8,          &Bs[0][0][0]   + idx_w*8);
    }
    #pragma unroll
    for (int q = 0; q < 2; ++q) {
        const int idx_w = q*512 + wave*64;
        const int row = (idx_w >> 3) + sr;
        gload16(A + (size_t)(brow + 128 + row)*KDIM + sslot*8,    &As[0][128][0] + idx_w*8);
    }
    #pragma unroll
    for (int q = 0; q < 2; ++q) {
        const int idx_w = q*512 + wave*64;
        const int row = (idx_w >> 3) + sr;
        gload16(B + (size_t)(bcol + 128 + row)*KDIM + sslot*8,    &Bs[0][128][0] + idx_w*8);
    }
    #pragma unroll
    for (int q = 0; q < 2; ++q) {
        const int idx_w = q*512 + wave*64;
        const int row = (idx_w >> 3) + sr;
        gload16(A + (size_t)(brow + row)*KDIM + 64 + sslot*8,     &As[1][0][0]   + idx_w*8);
    }
    #pragma unroll
    for (int q = 0; q < 2; ++q) {
        const int idx_w = q*512 + wave*64;
        const int row = (idx_w >> 3) + sr;
        gload16(B + (size_t)(bcol + row)*KDIM + 64 + sslot*8,     &Bs[1][0][0]   + idx_w*8);
    }
    asm volatile("s_waitcnt vmcnt(4)" ::: "memory");
    __builtin_amdgcn_s_barrier();
    __builtin_amdgcn_sched_barrier(0);

    // ---- main loop ----
    #pragma unroll 1
    for (int t = 0; t < NT - 2; ++t)
        ktile2<KDIM, true, true, 4>(t, A, B, As, Bs, brow, bcol, wave, lane, wm, wn, fr, acc);
    ktile2<KDIM, true,  false, 0>(NT-2, A, B, As, Bs, brow, bcol, wave, lane, wm, wn, fr, acc);
    ktile2<KDIM, false, false, -1>(NT-1, A, B, As, Bs, brow, bcol, wave, lane, wm, wn, fr, acc);

    // ---- epilogue (nontemporal stream-out) ----
    if constexpr (EPI == 1) {
        u16* H = (u16*)OUT;
        const int Nh = Ncols >> 1;
        #pragma unroll
        for (int qm = 0; qm < 2; ++qm)
            #pragma unroll
            for (int m = 0; m < 4; ++m) {
                const int row = brow + qm*128 + wm*64 + m*16 + fq*4;
                #pragma unroll
                for (int qn = 0; qn < 2; ++qn) {
                    const int col = (bcol >> 1) + qn*64 + wn*16 + fr;
                    f32x4 g = acc[qm*4+m][qn*2+0];
                    f32x4 u = acc[qm*4+m][qn*2+1];
                    #pragma unroll
                    for (int r = 0; r < 4; ++r) {
                        float gv = g[r], uv = u[r];
                        float hv = (gv / (1.f + __expf(-gv))) * uv;
                        __builtin_nontemporal_store(f2bf(hv), &H[(size_t)(row + r) * Nh + col]);
                    }
                }
            }
    } else {
        float* Of = (float*)OUT;
        #pragma unroll
        for (int mi = 0; mi < 8; ++mi) {
            const int row = brow + (mi>>2)*128 + wm*64 + (mi&3)*16 + fq*4;
            #pragma unroll
            for (int ni = 0; ni < 4; ++ni) {
                const int col = bcol + (ni>>1)*128 + wn*32 + (ni&1)*16 + fr;
                #pragma unroll
                for (int r = 0; r < 4; ++r) {
                    float xv = __builtin_nontemporal_load(&X[(size_t)(row+r)*Ncols + col]);
                    __builtin_nontemporal_store(xv + acc[mi][ni][r], &Of[(size_t)(row+r)*Ncols + col]);
                }
            }
        }
    }
}

// ---------------- launch ----------------
extern "C" void kernel_launch(void* const* d_in, const int* in_sizes, int n_in,
                              void* d_out, int out_size, void* d_ws, size_t ws_size,
                              hipStream_t stream) {
    const float* x     = (const float*)d_in[0];
    const float* iw    = (const float*)d_in[1];
    const float* gg    = (const float*)d_in[2];
    const float* lnw   = (const float*)d_in[3];
    const float* lnb   = (const float*)d_in[4];
    const float* wgate = (const float*)d_in[5];
    const float* wup   = (const float*)d_in[6];
    const float* wdown = (const float*)d_in[7];
    float* out = (float*)d_out;

    const int ntok = in_sizes[0] / (8 * D_DIM);   // 4096
    const int M    = ntok * 8;                    // 32768

    const size_t flat_b = (size_t)M * D_DIM * 2;          //  64 MiB
    const size_t wc_b   = (size_t)2 * D_DIM * F_DIM * 2;  //  16 MiB (combined gate+up)
    const size_t wd_b   = (size_t)D_DIM * F_DIM * 2;      //   8 MiB
    const size_t h_b    = (size_t)M * F_DIM * 2;          // 256 MiB
    const size_t need   = flat_b + wc_b + wd_b + h_b;
    if (ws_size < need) return;

    char* ws = (char*)d_ws;
    u16* flat = (u16*)(ws);
    u16* wc   = (u16*)(ws + flat_b);
    u16* wdt  = (u16*)(ws + flat_b + wc_b);
    u16* h    = (u16*)(ws + flat_b + wc_b + wd_b);

    transpose_kernel<<<dim3(F_DIM/32, D_DIM/32), 256, 0, stream>>>(wgate, wc,  D_DIM, F_DIM, 1);
    transpose_kernel<<<dim3(F_DIM/32, D_DIM/32), 256, 0, stream>>>(wup,   wc,  D_DIM, F_DIM, 2);
    transpose_kernel<<<dim3(D_DIM/32, F_DIM/32), 256, 0, stream>>>(wdown, wdt, F_DIM, D_DIM, 0);
    geo_ln_kernel<<<dim3(ntok), 256, 0, stream>>>(x, iw, gg, lnw, lnb, flat);

    // GEMM1: [32768][1024] x [8192][1024]^T -> swiglu-pack -> h [32768][4096]
    gemm8ph<D_DIM, 1><<<dim3((M/256) * (2*F_DIM/256)), 512, 0, stream>>>(flat, wc, nullptr, h, 2*F_DIM);
    // GEMM2: [32768][4096] x [1024][4096]^T + x -> out [32768][1024]
    gemm8ph<F_DIM, 0><<<dim3((M/256) * (D_DIM/256)), 512, 0, stream>>>(h, wdt, x, out, D_DIM);
}